// Round 1
// baseline (3467.019 us; speedup 1.0000x reference)
//
#include <hip/hip_runtime.h>
#include <math.h>

// Problem constants (fixed by the reference).
constexpr int RVQ_N = 262144;
constexpr int RVQ_D = 64;
constexpr int RVQ_L = 4;
constexpr int RVQ_K = 1024;

// ---------------------------------------------------------------------------
// Kernel A: per-center squared norms, cnorm[l*K + k] = sum_d c[l][k][d]^2
// L*K = 4096 centers, one thread each.
// ---------------------------------------------------------------------------
__global__ __launch_bounds__(256) void rvq_cnorm_kernel(
    const float* __restrict__ cb, float* __restrict__ cnorm) {
  int i = blockIdx.x * blockDim.x + threadIdx.x;  // 0 .. L*K-1
  const float* c = cb + (size_t)i * RVQ_D;
  float a0 = 0.f, a1 = 0.f, a2 = 0.f, a3 = 0.f;
#pragma unroll
  for (int d = 0; d < RVQ_D; d += 4) {
    float4 v = *reinterpret_cast<const float4*>(c + d);
    a0 = fmaf(v.x, v.x, a0);
    a1 = fmaf(v.y, v.y, a1);
    a2 = fmaf(v.z, v.z, a2);
    a3 = fmaf(v.w, v.w, a3);
  }
  cnorm[i] = (a0 + a1) + (a2 + a3);
}

// ---------------------------------------------------------------------------
// Kernel B: fused 4-level residual VQ. One thread per point; residual r[64]
// lives in VGPRs. Codebook + cnorm reads use wave-uniform indices so the
// compiler emits s_load (scalar cache) -> inner loop stays pure v_fmac_f32.
// ---------------------------------------------------------------------------
__global__ __launch_bounds__(256) void rvq_main_kernel(
    const float* __restrict__ feat, const float* __restrict__ cb,
    const float* __restrict__ cnorm, float* __restrict__ out_q,
    float* __restrict__ out_idx) {
  const int n = blockIdx.x * 256 + threadIdx.x;  // grid sized exactly to N

  // Load this point's feature row (256 B contiguous per thread).
  const float4* f4 = reinterpret_cast<const float4*>(feat + (size_t)n * RVQ_D);
  float r[RVQ_D];
#pragma unroll
  for (int i = 0; i < RVQ_D / 4; ++i) {
    float4 v = f4[i];
    r[4 * i + 0] = v.x;
    r[4 * i + 1] = v.y;
    r[4 * i + 2] = v.z;
    r[4 * i + 3] = v.w;
  }

  for (int l = 0; l < RVQ_L; ++l) {
    const float* c = cb + (size_t)l * RVQ_K * RVQ_D;     // uniform
    const float* cn = cnorm + (size_t)l * RVQ_K;         // uniform

    // rr = ||r||^2 (mirrors reference's  rr - 2*dot + cc  association)
    float s0 = 0.f, s1 = 0.f, s2 = 0.f, s3 = 0.f;
#pragma unroll
    for (int i = 0; i < RVQ_D / 4; ++i) {
      s0 = fmaf(r[4 * i + 0], r[4 * i + 0], s0);
      s1 = fmaf(r[4 * i + 1], r[4 * i + 1], s1);
      s2 = fmaf(r[4 * i + 2], r[4 * i + 2], s2);
      s3 = fmaf(r[4 * i + 3], r[4 * i + 3], s3);
    }
    const float rr = (s0 + s1) + (s2 + s3);

    float best = INFINITY;
    int bidx = 0;
    for (int k = 0; k < RVQ_K; ++k) {
      const float4* c4 = reinterpret_cast<const float4*>(c + (size_t)k * RVQ_D);
      float a0 = 0.f, a1 = 0.f, a2 = 0.f, a3 = 0.f;
#pragma unroll
      for (int i = 0; i < RVQ_D / 4; ++i) {
        float4 v = c4[i];  // wave-uniform -> s_load_dwordx4
        a0 = fmaf(r[4 * i + 0], v.x, a0);
        a1 = fmaf(r[4 * i + 1], v.y, a1);
        a2 = fmaf(r[4 * i + 2], v.z, a2);
        a3 = fmaf(r[4 * i + 3], v.w, a3);
      }
      const float dot = (a0 + a1) + (a2 + a3);
      const float score = (rr - 2.0f * dot) + cn[k];  // uniform cnorm load
      if (score < best) {  // strict < == argmin first-min tie-break
        best = score;
        bidx = k;
      }
    }

    // Gather chosen center (per-lane divergent index; 256 B contiguous, L2-hot)
    const float4* q4 =
        reinterpret_cast<const float4*>(c + (size_t)bidx * RVQ_D);
#pragma unroll
    for (int i = 0; i < RVQ_D / 4; ++i) {
      float4 v = q4[i];
      r[4 * i + 0] -= v.x;
      r[4 * i + 1] -= v.y;
      r[4 * i + 2] -= v.z;
      r[4 * i + 3] -= v.w;
    }

    // indices output, level-major [L, N]; written as float values
    out_idx[(size_t)l * RVQ_N + n] = (float)bidx;
  }

  // quantized_result = features - final residual (exact algebraic identity;
  // fp rounding diff vs sum-of-levels is ~1e-6, threshold is ~20)
  float4* o4 = reinterpret_cast<float4*>(out_q + (size_t)n * RVQ_D);
#pragma unroll
  for (int i = 0; i < RVQ_D / 4; ++i) {
    float4 v = f4[i];
    float4 o;
    o.x = v.x - r[4 * i + 0];
    o.y = v.y - r[4 * i + 1];
    o.z = v.z - r[4 * i + 2];
    o.w = v.w - r[4 * i + 3];
    o4[i] = o;
  }
}

extern "C" void kernel_launch(void* const* d_in, const int* in_sizes, int n_in,
                              void* d_out, int out_size, void* d_ws,
                              size_t ws_size, hipStream_t stream) {
  const float* features = (const float*)d_in[0];   // [N, D]
  const float* codebooks = (const float*)d_in[1];  // [L, K, D]
  float* out_q = (float*)d_out;                    // [N, D]
  float* out_idx = (float*)d_out + (size_t)RVQ_N * RVQ_D;  // [L, N]
  float* cnorm = (float*)d_ws;                     // [L, K] scratch

  hipLaunchKernelGGL(rvq_cnorm_kernel, dim3((RVQ_L * RVQ_K) / 256), dim3(256),
                     0, stream, codebooks, cnorm);
  hipLaunchKernelGGL(rvq_main_kernel, dim3(RVQ_N / 256), dim3(256), 0, stream,
                     features, codebooks, cnorm, out_q, out_idx);
}

// Round 4
// 1323.219 us; speedup vs baseline: 2.6201x; 2.6201x over previous
//
#include <hip/hip_runtime.h>
#include <math.h>

constexpr int RVQ_N = 262144;
constexpr int RVQ_D = 64;
constexpr int RVQ_L = 4;
constexpr int RVQ_K = 1024;

typedef __attribute__((ext_vector_type(8))) short short8;
typedef __attribute__((ext_vector_type(4))) float floatx4;

// ---- exact 3-way bf16 split helpers (RNE) ----
__device__ __forceinline__ unsigned short f2bf(float f) {
  unsigned int u = __float_as_uint(f);
  u += 0x7fffu + ((u >> 16) & 1u);
  return (unsigned short)(u >> 16);
}
__device__ __forceinline__ float bf2f(unsigned short h) {
  return __uint_as_float(((unsigned int)h) << 16);
}
__device__ __forceinline__ void split3(float x, unsigned short& h0,
                                       unsigned short& h1,
                                       unsigned short& h2) {
  h0 = f2bf(x);
  float r1 = x - bf2f(h0);
  h1 = f2bf(r1);
  float r2 = r1 - bf2f(h1);
  h2 = f2bf(r2);
}

// ---------------------------------------------------------------------------
// Prep 1: split -2*codebook into 3 bf16 component arrays [L*K*D each]
// ---------------------------------------------------------------------------
__global__ __launch_bounds__(256) void rvq_prep_split(
    const float* __restrict__ cb, unsigned short* __restrict__ bh,
    unsigned short* __restrict__ bm, unsigned short* __restrict__ bl) {
  int i = blockIdx.x * 256 + threadIdx.x;
  float c2 = -2.0f * cb[i];
  unsigned short h0, h1, h2;
  split3(c2, h0, h1, h2);
  bh[i] = h0;
  bm[i] = h1;
  bl[i] = h2;
}

// ---------------------------------------------------------------------------
// Prep 2: per-center squared norms (identical arithmetic to the R1 kernel)
// ---------------------------------------------------------------------------
__global__ __launch_bounds__(256) void rvq_cnorm_kernel(
    const float* __restrict__ cb, float* __restrict__ cnorm) {
  int i = blockIdx.x * blockDim.x + threadIdx.x;
  const float* c = cb + (size_t)i * RVQ_D;
  float a0 = 0.f, a1 = 0.f, a2 = 0.f, a3 = 0.f;
#pragma unroll
  for (int d = 0; d < RVQ_D; d += 4) {
    float4 v = *reinterpret_cast<const float4*>(c + d);
    a0 = fmaf(v.x, v.x, a0);
    a1 = fmaf(v.y, v.y, a1);
    a2 = fmaf(v.z, v.z, a2);
    a3 = fmaf(v.w, v.w, a3);
  }
  cnorm[i] = (a0 + a1) + (a2 + a3);
}

// Rotated d-major LDS address: bank-conflict-free (<=2-way) for both the
// quad-split fragment regen and the per-lane (point-major) rescue access.
__device__ __forceinline__ int raddr(int wbase, int p, int d) {
  return d * 256 + wbase + ((p + d) & 63);
}

// Butterfly merge of sorted top-2 lists across the 16 column-lanes (bits 0-3).
__device__ __forceinline__ void merge16(float& a1, int& ai1, float& a2,
                                        int& ai2) {
#pragma unroll
  for (int off = 1; off <= 8; off <<= 1) {
    float ob1 = __shfl_xor(a1, off);
    int oi1 = __shfl_xor(ai1, off);
    float ob2 = __shfl_xor(a2, off);
    int oi2 = __shfl_xor(ai2, off);
    bool aw = (a1 < ob1) || (a1 == ob1 && ai1 <= oi1);
    float w1 = aw ? a1 : ob1;
    int wi1 = aw ? ai1 : oi1;
    float l1 = aw ? ob1 : a1;
    int li1 = aw ? oi1 : ai1;
    float w2 = aw ? a2 : ob2;
    int wi2 = aw ? ai2 : oi2;
    bool sw = (l1 < w2) || (l1 == w2 && li1 < wi2);
    a1 = w1;
    ai1 = wi1;
    a2 = sw ? l1 : w2;
    ai2 = sw ? li1 : wi2;
  }
}

// ---------------------------------------------------------------------------
// Main fused kernel. One wave = 64 points. MFMA split-bf16 scan nominates
// top-4 candidates per point; a per-lane rescue replicating the (empirically
// numpy-exact) R1 fp32 scoring decides. Residual chain fp32 in LDS.
// ---------------------------------------------------------------------------
__global__ __launch_bounds__(256, 2) void rvq_mfma_kernel(
    const float* __restrict__ feat, const float* __restrict__ cb,
    const unsigned short* __restrict__ cb_hi,
    const unsigned short* __restrict__ cb_mid,
    const unsigned short* __restrict__ cb_lo,
    const float* __restrict__ cnorm, float* __restrict__ out_q,
    float* __restrict__ out_idx) {
  __shared__ float rlds[RVQ_D * 256];  // 64 KB, rotated d-major

  const int tid = threadIdx.x;
  const int lane = tid & 63;
  const int wave = tid >> 6;
  const int wbase = wave * 64;
  const int m = lane & 15;  // column index (B center / C col / A row)
  const int q = lane >> 4;  // quad: k-octet / C row-group
  const int g = blockIdx.x * 256 + tid;  // this lane's own point (rescue)

  // ---- init: features -> rotated LDS residual ----
  {
    const float4* f4 = (const float4*)(feat + (size_t)g * RVQ_D);
#pragma unroll
    for (int i = 0; i < 16; ++i) {
      float4 v = f4[i];
      rlds[raddr(wbase, lane, 4 * i + 0)] = v.x;
      rlds[raddr(wbase, lane, 4 * i + 1)] = v.y;
      rlds[raddr(wbase, lane, 4 * i + 2)] = v.z;
      rlds[raddr(wbase, lane, 4 * i + 3)] = v.w;
    }
  }
  __syncthreads();

  // kept products: hi*hi, hi*mid, mid*hi, mid*mid, hi*lo, lo*hi
  constexpr int AC[6] = {0, 0, 1, 1, 0, 2};
  constexpr int BC[6] = {0, 1, 0, 1, 2, 0};

  for (int l = 0; l < RVQ_L; ++l) {
    const unsigned short* bh = cb_hi + (size_t)l * RVQ_K * RVQ_D;
    const unsigned short* bmp = cb_mid + (size_t)l * RVQ_K * RVQ_D;
    const unsigned short* blp = cb_lo + (size_t)l * RVQ_K * RVQ_D;
    const float* cnl = cnorm + (size_t)l * RVQ_K;
    const float* cbl = cb + (size_t)l * RVQ_K * RVQ_D;

    // ---- regen A-fragments from the fp32 residual ----
    short8 afr[4][3][2];
#pragma unroll
    for (int t = 0; t < 4; ++t)
#pragma unroll
      for (int oct = 0; oct < 2; ++oct)
#pragma unroll
        for (int j = 0; j < 8; ++j) {
          int d = oct * 32 + q * 8 + j;
          float x = rlds[raddr(wbase, t * 16 + m, d)];
          unsigned short h0, h1, h2;
          split3(x, h0, h1, h2);
          afr[t][0][oct][j] = (short)h0;
          afr[t][1][oct][j] = (short)h1;
          afr[t][2][oct][j] = (short)h2;
        }

    // ---- MFMA scan with per-lane (per-column) top-2 ----
    float m1[4][4], m2v[4][4];
    int i1[4][4], i2v[4][4];
#pragma unroll
    for (int t = 0; t < 4; ++t)
#pragma unroll
      for (int r2 = 0; r2 < 4; ++r2) {
        m1[t][r2] = INFINITY;
        m2v[t][r2] = INFINITY;
        i1[t][r2] = 0;
        i2v[t][r2] = 0;
      }

    for (int nt = 0; nt < RVQ_K / 16; ++nt) {
      size_t rowoff = (size_t)(nt * 16 + m) * RVQ_D + q * 8;
      short8 bcur[3][2];
      bcur[0][0] = *(const short8*)(bh + rowoff);
      bcur[0][1] = *(const short8*)(bh + rowoff + 32);
      bcur[1][0] = *(const short8*)(bmp + rowoff);
      bcur[1][1] = *(const short8*)(bmp + rowoff + 32);
      bcur[2][0] = *(const short8*)(blp + rowoff);
      bcur[2][1] = *(const short8*)(blp + rowoff + 32);
      float ccur = cnl[nt * 16 + m];

      floatx4 acc[4];
#pragma unroll
      for (int t = 0; t < 4; ++t) {
        acc[t][0] = ccur;
        acc[t][1] = ccur;
        acc[t][2] = ccur;
        acc[t][3] = ccur;
      }
#pragma unroll
      for (int s = 0; s < 6; ++s)
#pragma unroll
        for (int oct = 0; oct < 2; ++oct)
#pragma unroll
          for (int t = 0; t < 4; ++t)
            acc[t] = __builtin_amdgcn_mfma_f32_16x16x32_bf16(
                afr[t][AC[s]][oct], bcur[BC[s]][oct], acc[t], 0, 0, 0);

      int kidx = nt * 16 + m;
#pragma unroll
      for (int t = 0; t < 4; ++t)
#pragma unroll
        for (int r2 = 0; r2 < 4; ++r2) {
          float sc = acc[t][r2];
          float om1 = m1[t][r2], om2 = m2v[t][r2];
          int oi1 = i1[t][r2], oi2 = i2v[t][r2];
          bool b1 = sc < om1;
          bool b2 = (sc < om2) || (sc == om1);  // accept exact ties to slot 2
          m1[t][r2] = b1 ? sc : om1;
          i1[t][r2] = b1 ? kidx : oi1;
          m2v[t][r2] = b1 ? om1 : (b2 ? sc : om2);
          i2v[t][r2] = b1 ? oi1 : (b2 ? kidx : oi2);
        }
    }

    // ---- top-4 per point: global top-2, mask, re-merge for 3rd/4th ----
    int cand[4] = {0, 0, 0, 0};
    const int srcl = ((lane >> 2) & 3) << 4;  // quad holding my point's rows
#pragma unroll
    for (int t = 0; t < 4; ++t)
#pragma unroll
      for (int r2 = 0; r2 < 4; ++r2) {
        float p1 = m1[t][r2], p2 = m2v[t][r2];
        int gi1 = i1[t][r2], gi2 = i2v[t][r2];
        merge16(p1, gi1, p2, gi2);  // global top-2 of the 16 columns
        float x1 = m1[t][r2], x2 = m2v[t][r2];
        int y1 = i1[t][r2], y2 = i2v[t][r2];
        if (y1 == gi1 || y1 == gi2) x1 = INFINITY;
        if (y2 == gi1 || y2 == gi2) x2 = INFINITY;
        if (x2 < x1 || (x2 == x1 && y2 < y1)) {
          float tf = x1; x1 = x2; x2 = tf;
          int ti = y1; y1 = y2; y2 = ti;
        }
        merge16(x1, y1, x2, y2);  // top-2 of the remainder
        int v1 = __shfl(gi1, srcl);
        int v2 = __shfl(gi2, srcl);
        int v3 = __shfl(y1, srcl);
        int v4 = __shfl(y2, srcl);
        bool take = (q == t) && ((lane & 3) == r2);
        cand[0] = take ? v1 : cand[0];
        cand[1] = take ? v2 : cand[1];
        cand[2] = take ? v3 : cand[2];
        cand[3] = take ? v4 : cand[3];
      }

    // ---- exact fp32 rescue, replicating R1's scoring verbatim ----
    // sort candidates ascending (strict-< scan => smallest-index tie-break)
    {
      int tmp;
      if (cand[0] > cand[1]) { tmp = cand[0]; cand[0] = cand[1]; cand[1] = tmp; }
      if (cand[2] > cand[3]) { tmp = cand[2]; cand[2] = cand[3]; cand[3] = tmp; }
      if (cand[0] > cand[2]) { tmp = cand[0]; cand[0] = cand[2]; cand[2] = tmp; }
      if (cand[1] > cand[3]) { tmp = cand[1]; cand[1] = cand[3]; cand[3] = tmp; }
      if (cand[1] > cand[2]) { tmp = cand[1]; cand[1] = cand[2]; cand[2] = tmp; }
    }

    float r_[RVQ_D];
#pragma unroll
    for (int d = 0; d < RVQ_D; ++d) r_[d] = rlds[raddr(wbase, lane, d)];

    float s0 = 0.f, s1 = 0.f, s2 = 0.f, s3 = 0.f;
#pragma unroll
    for (int i = 0; i < 16; ++i) {
      s0 = fmaf(r_[4 * i + 0], r_[4 * i + 0], s0);
      s1 = fmaf(r_[4 * i + 1], r_[4 * i + 1], s1);
      s2 = fmaf(r_[4 * i + 2], r_[4 * i + 2], s2);
      s3 = fmaf(r_[4 * i + 3], r_[4 * i + 3], s3);
    }
    const float rr = (s0 + s1) + (s2 + s3);

    float best = INFINITY;
    int ci = 0;
#pragma unroll
    for (int jc = 0; jc < 4; ++jc) {
      int k = cand[jc];
      const float4* c4 = (const float4*)(cbl + (size_t)k * RVQ_D);
      float a0 = 0.f, a1 = 0.f, a2 = 0.f, a3 = 0.f;
#pragma unroll
      for (int i = 0; i < 16; ++i) {
        float4 v = c4[i];
        a0 = fmaf(r_[4 * i + 0], v.x, a0);
        a1 = fmaf(r_[4 * i + 1], v.y, a1);
        a2 = fmaf(r_[4 * i + 2], v.z, a2);
        a3 = fmaf(r_[4 * i + 3], v.w, a3);
      }
      float dot = (a0 + a1) + (a2 + a3);
      float score = (rr - 2.0f * dot) + cnl[k];
      if (score < best) {
        best = score;
        ci = k;
      }
    }

    // ---- exact fp32 residual update / output ----
    const float4* crow = (const float4*)(cbl + (size_t)ci * RVQ_D);
    if (l < RVQ_L - 1) {
#pragma unroll
      for (int i = 0; i < 16; ++i) {
        float4 v = crow[i];
        rlds[raddr(wbase, lane, 4 * i + 0)] = r_[4 * i + 0] - v.x;
        rlds[raddr(wbase, lane, 4 * i + 1)] = r_[4 * i + 1] - v.y;
        rlds[raddr(wbase, lane, 4 * i + 2)] = r_[4 * i + 2] - v.z;
        rlds[raddr(wbase, lane, 4 * i + 3)] = r_[4 * i + 3] - v.w;
      }
    } else {
      const float4* f4 = (const float4*)(feat + (size_t)g * RVQ_D);
      float4* o4 = (float4*)(out_q + (size_t)g * RVQ_D);
#pragma unroll
      for (int i = 0; i < 16; ++i) {
        float4 v = crow[i];
        float4 f = f4[i];
        float rn0 = r_[4 * i + 0] - v.x;
        float rn1 = r_[4 * i + 1] - v.y;
        float rn2 = r_[4 * i + 2] - v.z;
        float rn3 = r_[4 * i + 3] - v.w;
        float4 o;
        o.x = f.x - rn0;
        o.y = f.y - rn1;
        o.z = f.z - rn2;
        o.w = f.w - rn3;
        o4[i] = o;
      }
    }
    out_idx[(size_t)l * RVQ_N + g] = (float)ci;
    __syncthreads();
  }
}

extern "C" void kernel_launch(void* const* d_in, const int* in_sizes, int n_in,
                              void* d_out, int out_size, void* d_ws,
                              size_t ws_size, hipStream_t stream) {
  const float* features = (const float*)d_in[0];   // [N, D]
  const float* codebooks = (const float*)d_in[1];  // [L, K, D]
  float* out_q = (float*)d_out;                    // [N, D]
  float* out_idx = (float*)d_out + (size_t)RVQ_N * RVQ_D;  // [L, N]

  const size_t comp_elems = (size_t)RVQ_L * RVQ_K * RVQ_D;  // 262144
  unsigned short* cb_hi = (unsigned short*)d_ws;
  unsigned short* cb_mid = cb_hi + comp_elems;
  unsigned short* cb_lo = cb_mid + comp_elems;
  float* cnorm = (float*)(cb_lo + comp_elems);  // [L*K]

  hipLaunchKernelGGL(rvq_prep_split, dim3(comp_elems / 256), dim3(256), 0,
                     stream, codebooks, cb_hi, cb_mid, cb_lo);
  hipLaunchKernelGGL(rvq_cnorm_kernel, dim3((RVQ_L * RVQ_K) / 256), dim3(256),
                     0, stream, codebooks, cnorm);
  hipLaunchKernelGGL(rvq_mfma_kernel, dim3(RVQ_N / 256), dim3(256), 0, stream,
                     features, codebooks, cb_hi, cb_mid, cb_lo, cnorm, out_q,
                     out_idx);
}

// Round 5
// 1102.289 us; speedup vs baseline: 3.1453x; 1.2004x over previous
//
#include <hip/hip_runtime.h>
#include <math.h>

constexpr int RVQ_N = 262144;
constexpr int RVQ_D = 64;
constexpr int RVQ_L = 4;
constexpr int RVQ_K = 1024;

typedef __attribute__((ext_vector_type(8))) short short8;
typedef __attribute__((ext_vector_type(4))) float floatx4;

// ---- bf16 split helpers (RNE) ----
__device__ __forceinline__ unsigned short f2bf(float f) {
  unsigned int u = __float_as_uint(f);
  u += 0x7fffu + ((u >> 16) & 1u);
  return (unsigned short)(u >> 16);
}
__device__ __forceinline__ float bf2f(unsigned short h) {
  return __uint_as_float(((unsigned int)h) << 16);
}
__device__ __forceinline__ void split2(float x, unsigned short& h0,
                                       unsigned short& h1) {
  h0 = f2bf(x);
  float r1 = x - bf2f(h0);
  h1 = f2bf(r1);
}

// ---------------------------------------------------------------------------
// Prep 1: split -2*codebook into hi/mid bf16 arrays [L*K*D each]
// ---------------------------------------------------------------------------
__global__ __launch_bounds__(256) void rvq_prep_split(
    const float* __restrict__ cb, unsigned short* __restrict__ bh,
    unsigned short* __restrict__ bm) {
  int i = blockIdx.x * 256 + threadIdx.x;
  float c2 = -2.0f * cb[i];
  unsigned short h0, h1;
  split2(c2, h0, h1);
  bh[i] = h0;
  bm[i] = h1;
}

// ---------------------------------------------------------------------------
// Prep 2: per-center squared norms (identical arithmetic to the R1 kernel)
// ---------------------------------------------------------------------------
__global__ __launch_bounds__(256) void rvq_cnorm_kernel(
    const float* __restrict__ cb, float* __restrict__ cnorm) {
  int i = blockIdx.x * blockDim.x + threadIdx.x;
  const float* c = cb + (size_t)i * RVQ_D;
  float a0 = 0.f, a1 = 0.f, a2 = 0.f, a3 = 0.f;
#pragma unroll
  for (int d = 0; d < RVQ_D; d += 4) {
    float4 v = *reinterpret_cast<const float4*>(c + d);
    a0 = fmaf(v.x, v.x, a0);
    a1 = fmaf(v.y, v.y, a1);
    a2 = fmaf(v.z, v.z, a2);
    a3 = fmaf(v.w, v.w, a3);
  }
  cnorm[i] = (a0 + a1) + (a2 + a3);
}

// Rotated d-major LDS address (<=2-way bank aliasing for both access shapes).
__device__ __forceinline__ int raddr(int wbase, int p, int d) {
  return d * 256 + wbase + ((p + d) & 63);
}

// Butterfly merge of sorted top-2 lists across the 16 column-lanes (bits 0-3).
__device__ __forceinline__ void merge16(float& a1, int& ai1, float& a2,
                                        int& ai2) {
#pragma unroll
  for (int off = 1; off <= 8; off <<= 1) {
    float ob1 = __shfl_xor(a1, off);
    int oi1 = __shfl_xor(ai1, off);
    float ob2 = __shfl_xor(a2, off);
    int oi2 = __shfl_xor(ai2, off);
    bool aw = (a1 < ob1) || (a1 == ob1 && ai1 <= oi1);
    float w1 = aw ? a1 : ob1;
    int wi1 = aw ? ai1 : oi1;
    float l1 = aw ? ob1 : a1;
    int li1 = aw ? oi1 : ai1;
    float w2 = aw ? a2 : ob2;
    int wi2 = aw ? ai2 : oi2;
    bool sw = (l1 < w2) || (l1 == w2 && li1 < wi2);
    a1 = w1;
    ai1 = wi1;
    a2 = sw ? l1 : w2;
    ai2 = sw ? li1 : wi2;
  }
}

// B-tile fragment loader: hi/mid x 2 dim-octets + cnorm
__device__ __forceinline__ void load_bt(const unsigned short* __restrict__ bh,
                                        const unsigned short* __restrict__ bmp,
                                        const float* __restrict__ cnl, int nt,
                                        int m, int q, short8 (&b)[2][2],
                                        float& cc) {
  size_t rowoff = (size_t)(nt * 16 + m) * RVQ_D + q * 8;
  b[0][0] = *(const short8*)(bh + rowoff);
  b[0][1] = *(const short8*)(bh + rowoff + 32);
  b[1][0] = *(const short8*)(bmp + rowoff);
  b[1][1] = *(const short8*)(bmp + rowoff + 32);
  cc = cnl[nt * 16 + m];
}

// ---------------------------------------------------------------------------
// Main fused kernel. One wave = 64 points. 3-product split-bf16 MFMA scan
// nominates top-4 per point; exact-fp32 rescue (R1-verbatim) decides.
// Residual chain fp32 in LDS (rotated layout).
// ---------------------------------------------------------------------------
__global__ __launch_bounds__(256, 2) void rvq_mfma_kernel(
    const float* __restrict__ feat, const float* __restrict__ cb,
    const unsigned short* __restrict__ cb_hi,
    const unsigned short* __restrict__ cb_mid,
    const float* __restrict__ cnorm, float* __restrict__ out_q,
    float* __restrict__ out_idx) {
  __shared__ float rlds[RVQ_D * 256];  // 64 KB

  const int tid = threadIdx.x;
  const int lane = tid & 63;
  const int wave = tid >> 6;
  const int wbase = wave * 64;
  const int m = lane & 15;
  const int q = lane >> 4;
  const int g = blockIdx.x * 256 + tid;

  // ---- init: features -> rotated LDS residual ----
  {
    const float4* f4 = (const float4*)(feat + (size_t)g * RVQ_D);
#pragma unroll
    for (int i = 0; i < 16; ++i) {
      float4 v = f4[i];
      rlds[raddr(wbase, lane, 4 * i + 0)] = v.x;
      rlds[raddr(wbase, lane, 4 * i + 1)] = v.y;
      rlds[raddr(wbase, lane, 4 * i + 2)] = v.z;
      rlds[raddr(wbase, lane, 4 * i + 3)] = v.w;
    }
  }
  __syncthreads();

  // products kept: hi*hi, hi*mid, mid*hi
  constexpr int AC[3] = {0, 0, 1};
  constexpr int BC[3] = {0, 1, 0};

  for (int l = 0; l < RVQ_L; ++l) {
    const unsigned short* bh = cb_hi + (size_t)l * RVQ_K * RVQ_D;
    const unsigned short* bmp = cb_mid + (size_t)l * RVQ_K * RVQ_D;
    const float* cnl = cnorm + (size_t)l * RVQ_K;
    const float* cbl = cb + (size_t)l * RVQ_K * RVQ_D;

    // ---- regen A-fragments (hi/mid) from the fp32 residual ----
    short8 afr[4][2][2];
#pragma unroll
    for (int t = 0; t < 4; ++t)
#pragma unroll
      for (int oct = 0; oct < 2; ++oct)
#pragma unroll
        for (int j = 0; j < 8; ++j) {
          int d = oct * 32 + q * 8 + j;
          float x = rlds[raddr(wbase, t * 16 + m, d)];
          unsigned short h0, h1;
          split2(x, h0, h1);
          afr[t][0][oct][j] = (short)h0;
          afr[t][1][oct][j] = (short)h1;
        }

    // ---- MFMA scan with per-column exact fp32 top-2, double-buffered ----
    float m1[4][4], m2v[4][4];
    int i1[4][4], i2v[4][4];
#pragma unroll
    for (int t = 0; t < 4; ++t)
#pragma unroll
      for (int r2 = 0; r2 < 4; ++r2) {
        m1[t][r2] = INFINITY;
        m2v[t][r2] = INFINITY;
        i1[t][r2] = 0;
        i2v[t][r2] = 0;
      }

    short8 bA[2][2], bB[2][2];
    float ccA, ccB;
    load_bt(bh, bmp, cnl, 0, m, q, bA, ccA);

    for (int nt = 0; nt < RVQ_K / 16; nt += 2) {
      // prefetch odd tile
      load_bt(bh, bmp, cnl, nt + 1, m, q, bB, ccB);

      // ---- even tile (bA) ----
      {
        floatx4 acc[4];
#pragma unroll
        for (int t = 0; t < 4; ++t) {
          acc[t][0] = ccA;
          acc[t][1] = ccA;
          acc[t][2] = ccA;
          acc[t][3] = ccA;
        }
#pragma unroll
        for (int s = 0; s < 3; ++s)
#pragma unroll
          for (int oct = 0; oct < 2; ++oct)
#pragma unroll
            for (int t = 0; t < 4; ++t)
              acc[t] = __builtin_amdgcn_mfma_f32_16x16x32_bf16(
                  afr[t][AC[s]][oct], bA[BC[s]][oct], acc[t], 0, 0, 0);
        int kidx = nt * 16 + m;
#pragma unroll
        for (int t = 0; t < 4; ++t)
#pragma unroll
          for (int r2 = 0; r2 < 4; ++r2) {
            float sc = acc[t][r2];
            float om1 = m1[t][r2];
            bool b1 = sc < om1;
            bool b2 = sc < m2v[t][r2];
            m1[t][r2] = fminf(sc, om1);
            m2v[t][r2] = fminf(fmaxf(sc, om1), m2v[t][r2]);
            i2v[t][r2] = b1 ? i1[t][r2] : (b2 ? kidx : i2v[t][r2]);
            i1[t][r2] = b1 ? kidx : i1[t][r2];
          }
      }

      // prefetch next even tile (clamped reload on the last pair)
      int ntn = (nt + 2 < RVQ_K / 16) ? nt + 2 : nt;
      load_bt(bh, bmp, cnl, ntn, m, q, bA, ccA);

      // ---- odd tile (bB) ----
      {
        floatx4 acc[4];
#pragma unroll
        for (int t = 0; t < 4; ++t) {
          acc[t][0] = ccB;
          acc[t][1] = ccB;
          acc[t][2] = ccB;
          acc[t][3] = ccB;
        }
#pragma unroll
        for (int s = 0; s < 3; ++s)
#pragma unroll
          for (int oct = 0; oct < 2; ++oct)
#pragma unroll
            for (int t = 0; t < 4; ++t)
              acc[t] = __builtin_amdgcn_mfma_f32_16x16x32_bf16(
                  afr[t][AC[s]][oct], bB[BC[s]][oct], acc[t], 0, 0, 0);
        int kidx = (nt + 1) * 16 + m;
#pragma unroll
        for (int t = 0; t < 4; ++t)
#pragma unroll
          for (int r2 = 0; r2 < 4; ++r2) {
            float sc = acc[t][r2];
            float om1 = m1[t][r2];
            bool b1 = sc < om1;
            bool b2 = sc < m2v[t][r2];
            m1[t][r2] = fminf(sc, om1);
            m2v[t][r2] = fminf(fmaxf(sc, om1), m2v[t][r2]);
            i2v[t][r2] = b1 ? i1[t][r2] : (b2 ? kidx : i2v[t][r2]);
            i1[t][r2] = b1 ? kidx : i1[t][r2];
          }
      }
    }

    // ---- top-4 per point: global top-2, mask, re-merge for 3rd/4th ----
    int cand[4] = {0, 0, 0, 0};
    const int srcl = ((lane >> 2) & 3) << 4;
#pragma unroll
    for (int t = 0; t < 4; ++t)
#pragma unroll
      for (int r2 = 0; r2 < 4; ++r2) {
        float p1 = m1[t][r2], p2 = m2v[t][r2];
        int gi1 = i1[t][r2], gi2 = i2v[t][r2];
        merge16(p1, gi1, p2, gi2);
        float x1 = m1[t][r2], x2 = m2v[t][r2];
        int y1 = i1[t][r2], y2 = i2v[t][r2];
        if (y1 == gi1 || y1 == gi2) x1 = INFINITY;
        if (y2 == gi1 || y2 == gi2) x2 = INFINITY;
        if (x2 < x1 || (x2 == x1 && y2 < y1)) {
          float tf = x1; x1 = x2; x2 = tf;
          int ti = y1; y1 = y2; y2 = ti;
        }
        merge16(x1, y1, x2, y2);
        int v1 = __shfl(gi1, srcl);
        int v2 = __shfl(gi2, srcl);
        int v3 = __shfl(y1, srcl);
        int v4 = __shfl(y2, srcl);
        bool take = (q == t) && ((lane & 3) == r2);
        cand[0] = take ? v1 : cand[0];
        cand[1] = take ? v2 : cand[1];
        cand[2] = take ? v3 : cand[2];
        cand[3] = take ? v4 : cand[3];
      }

    // ---- exact fp32 rescue, replicating R1's scoring verbatim ----
    {
      int tmp;
      if (cand[0] > cand[1]) { tmp = cand[0]; cand[0] = cand[1]; cand[1] = tmp; }
      if (cand[2] > cand[3]) { tmp = cand[2]; cand[2] = cand[3]; cand[3] = tmp; }
      if (cand[0] > cand[2]) { tmp = cand[0]; cand[0] = cand[2]; cand[2] = tmp; }
      if (cand[1] > cand[3]) { tmp = cand[1]; cand[1] = cand[3]; cand[3] = tmp; }
      if (cand[1] > cand[2]) { tmp = cand[1]; cand[1] = cand[2]; cand[2] = tmp; }
    }

    float r_[RVQ_D];
#pragma unroll
    for (int d = 0; d < RVQ_D; ++d) r_[d] = rlds[raddr(wbase, lane, d)];

    float s0 = 0.f, s1 = 0.f, s2 = 0.f, s3 = 0.f;
#pragma unroll
    for (int i = 0; i < 16; ++i) {
      s0 = fmaf(r_[4 * i + 0], r_[4 * i + 0], s0);
      s1 = fmaf(r_[4 * i + 1], r_[4 * i + 1], s1);
      s2 = fmaf(r_[4 * i + 2], r_[4 * i + 2], s2);
      s3 = fmaf(r_[4 * i + 3], r_[4 * i + 3], s3);
    }
    const float rr = (s0 + s1) + (s2 + s3);

    float best = INFINITY;
    int ci = 0;
#pragma unroll
    for (int jc = 0; jc < 4; ++jc) {
      int k = cand[jc];
      const float4* c4 = (const float4*)(cbl + (size_t)k * RVQ_D);
      float a0 = 0.f, a1 = 0.f, a2 = 0.f, a3 = 0.f;
#pragma unroll
      for (int i = 0; i < 16; ++i) {
        float4 v = c4[i];
        a0 = fmaf(r_[4 * i + 0], v.x, a0);
        a1 = fmaf(r_[4 * i + 1], v.y, a1);
        a2 = fmaf(r_[4 * i + 2], v.z, a2);
        a3 = fmaf(r_[4 * i + 3], v.w, a3);
      }
      float dot = (a0 + a1) + (a2 + a3);
      float score = (rr - 2.0f * dot) + cnl[k];
      if (score < best) {
        best = score;
        ci = k;
      }
    }

    // ---- exact fp32 residual update / output ----
    const float4* crow = (const float4*)(cbl + (size_t)ci * RVQ_D);
    if (l < RVQ_L - 1) {
#pragma unroll
      for (int i = 0; i < 16; ++i) {
        float4 v = crow[i];
        rlds[raddr(wbase, lane, 4 * i + 0)] = r_[4 * i + 0] - v.x;
        rlds[raddr(wbase, lane, 4 * i + 1)] = r_[4 * i + 1] - v.y;
        rlds[raddr(wbase, lane, 4 * i + 2)] = r_[4 * i + 2] - v.z;
        rlds[raddr(wbase, lane, 4 * i + 3)] = r_[4 * i + 3] - v.w;
      }
    } else {
      const float4* f4 = (const float4*)(feat + (size_t)g * RVQ_D);
      float4* o4 = (float4*)(out_q + (size_t)g * RVQ_D);
#pragma unroll
      for (int i = 0; i < 16; ++i) {
        float4 v = crow[i];
        float4 f = f4[i];
        float rn0 = r_[4 * i + 0] - v.x;
        float rn1 = r_[4 * i + 1] - v.y;
        float rn2 = r_[4 * i + 2] - v.z;
        float rn3 = r_[4 * i + 3] - v.w;
        float4 o;
        o.x = f.x - rn0;
        o.y = f.y - rn1;
        o.z = f.z - rn2;
        o.w = f.w - rn3;
        o4[i] = o;
      }
    }
    out_idx[(size_t)l * RVQ_N + g] = (float)ci;
    __syncthreads();
  }
}

extern "C" void kernel_launch(void* const* d_in, const int* in_sizes, int n_in,
                              void* d_out, int out_size, void* d_ws,
                              size_t ws_size, hipStream_t stream) {
  const float* features = (const float*)d_in[0];   // [N, D]
  const float* codebooks = (const float*)d_in[1];  // [L, K, D]
  float* out_q = (float*)d_out;                    // [N, D]
  float* out_idx = (float*)d_out + (size_t)RVQ_N * RVQ_D;  // [L, N]

  const size_t comp_elems = (size_t)RVQ_L * RVQ_K * RVQ_D;  // 262144
  unsigned short* cb_hi = (unsigned short*)d_ws;
  unsigned short* cb_mid = cb_hi + comp_elems;
  float* cnorm = (float*)(cb_mid + comp_elems);  // [L*K]

  hipLaunchKernelGGL(rvq_prep_split, dim3(comp_elems / 256), dim3(256), 0,
                     stream, codebooks, cb_hi, cb_mid);
  hipLaunchKernelGGL(rvq_cnorm_kernel, dim3((RVQ_L * RVQ_K) / 256), dim3(256),
                     0, stream, codebooks, cnorm);
  hipLaunchKernelGGL(rvq_mfma_kernel, dim3(RVQ_N / 256), dim3(256), 0, stream,
                     features, codebooks, cb_hi, cb_mid, cnorm, out_q,
                     out_idx);
}

// Round 6
// 974.556 us; speedup vs baseline: 3.5575x; 1.1311x over previous
//
#include <hip/hip_runtime.h>
#include <math.h>

constexpr int RVQ_N = 262144;
constexpr int RVQ_D = 64;
constexpr int RVQ_L = 4;
constexpr int RVQ_K = 1024;

typedef __attribute__((ext_vector_type(8))) short short8;
typedef __attribute__((ext_vector_type(4))) float floatx4;

// ---- bf16 split helpers (RNE) ----
__device__ __forceinline__ unsigned short f2bf(float f) {
  unsigned int u = __float_as_uint(f);
  u += 0x7fffu + ((u >> 16) & 1u);
  return (unsigned short)(u >> 16);
}
__device__ __forceinline__ float bf2f(unsigned short h) {
  return __uint_as_float(((unsigned int)h) << 16);
}
__device__ __forceinline__ void split2(float x, unsigned short& h0,
                                       unsigned short& h1) {
  h0 = f2bf(x);
  float r1 = x - bf2f(h0);
  h1 = f2bf(r1);
}
__device__ __forceinline__ void load8(const float* p, float* v) {
  float4 a = *(const float4*)p;
  float4 b = *(const float4*)(p + 4);
  v[0] = a.x; v[1] = a.y; v[2] = a.z; v[3] = a.w;
  v[4] = b.x; v[5] = b.y; v[6] = b.z; v[7] = b.w;
}

// ---------------------------------------------------------------------------
// Prep 1: split -2*codebook into hi/mid bf16 arrays [L*K*D each]
// ---------------------------------------------------------------------------
__global__ __launch_bounds__(256) void rvq_prep_split(
    const float* __restrict__ cb, unsigned short* __restrict__ bh,
    unsigned short* __restrict__ bm) {
  int i = blockIdx.x * 256 + threadIdx.x;
  float c2 = -2.0f * cb[i];
  unsigned short h0, h1;
  split2(c2, h0, h1);
  bh[i] = h0;
  bm[i] = h1;
}

// ---------------------------------------------------------------------------
// Prep 2: per-center squared norms. Raw (R1-verbatim, for rescue) + biased
// (+256 so MFMA scores = ||r-c||^2 + 256 > 0 -> uint-compare monotone).
// ---------------------------------------------------------------------------
__global__ __launch_bounds__(256) void rvq_cnorm_kernel(
    const float* __restrict__ cb, float* __restrict__ cnorm,
    float* __restrict__ cnormB) {
  int i = blockIdx.x * blockDim.x + threadIdx.x;
  const float* c = cb + (size_t)i * RVQ_D;
  float a0 = 0.f, a1 = 0.f, a2 = 0.f, a3 = 0.f;
#pragma unroll
  for (int d = 0; d < RVQ_D; d += 4) {
    float4 v = *reinterpret_cast<const float4*>(c + d);
    a0 = fmaf(v.x, v.x, a0);
    a1 = fmaf(v.y, v.y, a1);
    a2 = fmaf(v.z, v.z, a2);
    a3 = fmaf(v.w, v.w, a3);
  }
  float s = (a0 + a1) + (a2 + a3);
  cnorm[i] = s;
  cnormB[i] = s + 256.0f;
}

// B-tile fragment loader: hi/mid x 2 dim-octets + biased cnorm
__device__ __forceinline__ void load_bt(const unsigned short* __restrict__ bh,
                                        const unsigned short* __restrict__ bmp,
                                        const float* __restrict__ cnl, int nt,
                                        int m, int q, short8 (&b)[2][2],
                                        float& cc) {
  size_t rowoff = (size_t)(nt * 16 + m) * RVQ_D + q * 8;
  b[0][0] = *(const short8*)(bh + rowoff);
  b[0][1] = *(const short8*)(bh + rowoff + 32);
  b[1][0] = *(const short8*)(bmp + rowoff);
  b[1][1] = *(const short8*)(bmp + rowoff + 32);
  cc = cnl[nt * 16 + m];
}

// ---------------------------------------------------------------------------
// Main fused kernel. No LDS, no barriers. State per lane = its point's chosen
// index chain; residual is recomputed exactly ((f-c0)-c1)-c2 wherever needed
// (fragment regen in fragment layout; rescue in point layout). Packed-uint
// top-2 scan nominates; R1-verbatim fp32 rescue decides.
// ---------------------------------------------------------------------------
__global__ __launch_bounds__(256, 3) void rvq_mfma_kernel(
    const float* __restrict__ feat, const float* __restrict__ cb,
    const unsigned short* __restrict__ cb_hi,
    const unsigned short* __restrict__ cb_mid,
    const float* __restrict__ cnorm, const float* __restrict__ cnormB,
    float* __restrict__ out_q, float* __restrict__ out_idx) {
  const int tid = threadIdx.x;
  const int lane = tid & 63;
  const int wave = tid >> 6;
  const int m = lane & 15;  // column (B center / C col / A row)
  const int q = lane >> 4;  // quad (k-octet / C row-group)
  const int base = blockIdx.x * 256 + wave * 64;  // wave's first point
  const int g = base + lane;                      // this lane's own point

  int ci0 = 0, ci1 = 0, ci2 = 0;  // chosen-index chain (own point)

  // products kept: hi*hi, hi*mid, mid*hi
  constexpr int AC[3] = {0, 0, 1};
  constexpr int BC[3] = {0, 1, 0};

#pragma unroll
  for (int l = 0; l < RVQ_L; ++l) {
    const unsigned short* bh = cb_hi + (size_t)l * RVQ_K * RVQ_D;
    const unsigned short* bmp = cb_mid + (size_t)l * RVQ_K * RVQ_D;
    const float* cnBl = cnormB + (size_t)l * RVQ_K;
    const float* cnl = cnorm + (size_t)l * RVQ_K;
    const float* cbl = cb + (size_t)l * RVQ_K * RVQ_D;

    // ---- A-fragment regen from (features, chain), in fragment layout ----
    short8 afr[4][2][2];
#pragma unroll
    for (int t = 0; t < 4; ++t) {
      const int p = t * 16 + m;
      int j0 = 0, j1 = 0, j2 = 0;
      if (l > 0) j0 = __shfl(ci0, p);
      if (l > 1) j1 = __shfl(ci1, p);
      if (l > 2) j2 = __shfl(ci2, p);
      const float* fp = feat + (size_t)(base + p) * RVQ_D;
      const float* c0p = cb + (size_t)j0 * RVQ_D;
      const float* c1p = cb + ((size_t)RVQ_K + j1) * RVQ_D;
      const float* c2p = cb + ((size_t)2 * RVQ_K + j2) * RVQ_D;
#pragma unroll
      for (int oct = 0; oct < 2; ++oct) {
        const int dof = oct * 32 + q * 8;
        float v[8];
        load8(fp + dof, v);
        if (l > 0) {
          float c[8];
          load8(c0p + dof, c);
#pragma unroll
          for (int e = 0; e < 8; ++e) v[e] -= c[e];
        }
        if (l > 1) {
          float c[8];
          load8(c1p + dof, c);
#pragma unroll
          for (int e = 0; e < 8; ++e) v[e] -= c[e];
        }
        if (l > 2) {
          float c[8];
          load8(c2p + dof, c);
#pragma unroll
          for (int e = 0; e < 8; ++e) v[e] -= c[e];
        }
#pragma unroll
        for (int e = 0; e < 8; ++e) {
          unsigned short h0, h1;
          split2(v[e], h0, h1);
          afr[t][0][oct][e] = (short)h0;
          afr[t][1][oct][e] = (short)h1;
        }
      }
    }

    // ---- packed top-2 MFMA scan, double-buffered B ----
    unsigned p1[4][4], p2[4][4];
#pragma unroll
    for (int t = 0; t < 4; ++t)
#pragma unroll
      for (int r2 = 0; r2 < 4; ++r2) {
        p1[t][r2] = 0xFFFFFFFFu;
        p2[t][r2] = 0xFFFFFFFFu;
      }

    short8 bA[2][2], bB[2][2];
    float ccA, ccB;
    load_bt(bh, bmp, cnBl, 0, m, q, bA, ccA);

    for (int nt = 0; nt < RVQ_K / 16; nt += 2) {
      load_bt(bh, bmp, cnBl, nt + 1, m, q, bB, ccB);
      {  // even tile
        floatx4 acc[4];
#pragma unroll
        for (int t = 0; t < 4; ++t) {
          acc[t][0] = ccA; acc[t][1] = ccA; acc[t][2] = ccA; acc[t][3] = ccA;
        }
#pragma unroll
        for (int s = 0; s < 3; ++s)
#pragma unroll
          for (int oct = 0; oct < 2; ++oct)
#pragma unroll
            for (int t = 0; t < 4; ++t)
              acc[t] = __builtin_amdgcn_mfma_f32_16x16x32_bf16(
                  afr[t][AC[s]][oct], bA[BC[s]][oct], acc[t], 0, 0, 0);
        unsigned nbits = (unsigned)nt;
#pragma unroll
        for (int t = 0; t < 4; ++t)
#pragma unroll
          for (int r2 = 0; r2 < 4; ++r2) {
            unsigned u = (__float_as_uint(acc[t][r2]) & 0xFFFFFFC0u) | nbits;
            unsigned mx = p1[t][r2] > u ? p1[t][r2] : u;
            p1[t][r2] = p1[t][r2] < u ? p1[t][r2] : u;
            p2[t][r2] = p2[t][r2] < mx ? p2[t][r2] : mx;
          }
      }
      int ntn = (nt + 2 < RVQ_K / 16) ? nt + 2 : nt;
      load_bt(bh, bmp, cnBl, ntn, m, q, bA, ccA);
      {  // odd tile
        floatx4 acc[4];
#pragma unroll
        for (int t = 0; t < 4; ++t) {
          acc[t][0] = ccB; acc[t][1] = ccB; acc[t][2] = ccB; acc[t][3] = ccB;
        }
#pragma unroll
        for (int s = 0; s < 3; ++s)
#pragma unroll
          for (int oct = 0; oct < 2; ++oct)
#pragma unroll
            for (int t = 0; t < 4; ++t)
              acc[t] = __builtin_amdgcn_mfma_f32_16x16x32_bf16(
                  afr[t][AC[s]][oct], bB[BC[s]][oct], acc[t], 0, 0, 0);
        unsigned nbits = (unsigned)(nt + 1);
#pragma unroll
        for (int t = 0; t < 4; ++t)
#pragma unroll
          for (int r2 = 0; r2 < 4; ++r2) {
            unsigned u = (__float_as_uint(acc[t][r2]) & 0xFFFFFFC0u) | nbits;
            unsigned mx = p1[t][r2] > u ? p1[t][r2] : u;
            p1[t][r2] = p1[t][r2] < u ? p1[t][r2] : u;
            p2[t][r2] = p2[t][r2] < mx ? p2[t][r2] : mx;
          }
      }
    }

    // ---- top-4 per point via 4 masked butterfly-min passes ----
    int cand[4] = {0, 0, 0, 0};
    const int srcl = ((lane >> 2) & 3) << 4;
#pragma unroll
    for (int t = 0; t < 4; ++t)
#pragma unroll
      for (int r2 = 0; r2 < 4; ++r2) {
        unsigned a = p1[t][r2], b = p2[t][r2];
        int ka = (int)((a & 63u) << 4) | m;
        int kb = (int)((b & 63u) << 4) | m;
        unsigned va = (a & 0xFFFFFC00u) | (unsigned)ka;  // 10-bit k embedded
        unsigned vb = (b & 0xFFFFFC00u) | (unsigned)kb;
        if (vb < va) { unsigned tu = va; va = vb; vb = tu; }
        int ck[4];
#pragma unroll
        for (int pass = 0; pass < 4; ++pass) {
          unsigned gm = va;
#pragma unroll
          for (int off = 1; off <= 8; off <<= 1) {
            unsigned o = (unsigned)__shfl_xor((int)gm, off);
            gm = gm < o ? gm : o;
          }
          ck[pass] = (int)(gm & 1023u);
          bool hit = (va == gm);
          va = hit ? vb : va;
          vb = hit ? 0xFFFFFFFFu : vb;
        }
        int v1 = __shfl(ck[0], srcl);
        int v2 = __shfl(ck[1], srcl);
        int v3 = __shfl(ck[2], srcl);
        int v4 = __shfl(ck[3], srcl);
        bool take = (q == t) && ((lane & 3) == r2);
        if (take) { cand[0] = v1; cand[1] = v2; cand[2] = v3; cand[3] = v4; }
      }

    // ---- exact fp32 rescue (R1-verbatim scoring) on own point ----
    {
      int tmp;
      if (cand[0] > cand[1]) { tmp = cand[0]; cand[0] = cand[1]; cand[1] = tmp; }
      if (cand[2] > cand[3]) { tmp = cand[2]; cand[2] = cand[3]; cand[3] = tmp; }
      if (cand[0] > cand[2]) { tmp = cand[0]; cand[0] = cand[2]; cand[2] = tmp; }
      if (cand[1] > cand[3]) { tmp = cand[1]; cand[1] = cand[3]; cand[3] = tmp; }
      if (cand[1] > cand[2]) { tmp = cand[1]; cand[1] = cand[2]; cand[2] = tmp; }
    }

    float r_[RVQ_D];
    {
      const float4* f4p = (const float4*)(feat + (size_t)g * RVQ_D);
#pragma unroll
      for (int i = 0; i < 16; ++i) {
        float4 v = f4p[i];
        r_[4 * i + 0] = v.x; r_[4 * i + 1] = v.y;
        r_[4 * i + 2] = v.z; r_[4 * i + 3] = v.w;
      }
      if (l > 0) {
        const float4* cp = (const float4*)(cb + (size_t)ci0 * RVQ_D);
#pragma unroll
        for (int i = 0; i < 16; ++i) {
          float4 v = cp[i];
          r_[4 * i + 0] -= v.x; r_[4 * i + 1] -= v.y;
          r_[4 * i + 2] -= v.z; r_[4 * i + 3] -= v.w;
        }
      }
      if (l > 1) {
        const float4* cp = (const float4*)(cb + ((size_t)RVQ_K + ci1) * RVQ_D);
#pragma unroll
        for (int i = 0; i < 16; ++i) {
          float4 v = cp[i];
          r_[4 * i + 0] -= v.x; r_[4 * i + 1] -= v.y;
          r_[4 * i + 2] -= v.z; r_[4 * i + 3] -= v.w;
        }
      }
      if (l > 2) {
        const float4* cp =
            (const float4*)(cb + ((size_t)2 * RVQ_K + ci2) * RVQ_D);
#pragma unroll
        for (int i = 0; i < 16; ++i) {
          float4 v = cp[i];
          r_[4 * i + 0] -= v.x; r_[4 * i + 1] -= v.y;
          r_[4 * i + 2] -= v.z; r_[4 * i + 3] -= v.w;
        }
      }
    }

    float s0 = 0.f, s1 = 0.f, s2 = 0.f, s3 = 0.f;
#pragma unroll
    for (int i = 0; i < 16; ++i) {
      s0 = fmaf(r_[4 * i + 0], r_[4 * i + 0], s0);
      s1 = fmaf(r_[4 * i + 1], r_[4 * i + 1], s1);
      s2 = fmaf(r_[4 * i + 2], r_[4 * i + 2], s2);
      s3 = fmaf(r_[4 * i + 3], r_[4 * i + 3], s3);
    }
    const float rr = (s0 + s1) + (s2 + s3);

    float best = INFINITY;
    int ci = 0;
#pragma unroll
    for (int jc = 0; jc < 4; ++jc) {
      int k = cand[jc];
      const float4* c4 = (const float4*)(cbl + (size_t)k * RVQ_D);
      float a0 = 0.f, a1 = 0.f, a2 = 0.f, a3 = 0.f;
#pragma unroll
      for (int i = 0; i < 16; ++i) {
        float4 v = c4[i];
        a0 = fmaf(r_[4 * i + 0], v.x, a0);
        a1 = fmaf(r_[4 * i + 1], v.y, a1);
        a2 = fmaf(r_[4 * i + 2], v.z, a2);
        a3 = fmaf(r_[4 * i + 3], v.w, a3);
      }
      float dot = (a0 + a1) + (a2 + a3);
      float score = (rr - 2.0f * dot) + cnl[k];
      if (score < best) {
        best = score;
        ci = k;
      }
    }

    if (l == 0) ci0 = ci;
    else if (l == 1) ci1 = ci;
    else if (l == 2) ci2 = ci;

    if (l == RVQ_L - 1) {
      // out = features - final residual (rn = r - c_ci), exact fp32
      const float4* crow = (const float4*)(cbl + (size_t)ci * RVQ_D);
      const float4* f4p = (const float4*)(feat + (size_t)g * RVQ_D);
      float4* o4 = (float4*)(out_q + (size_t)g * RVQ_D);
#pragma unroll
      for (int i = 0; i < 16; ++i) {
        float4 cv = crow[i];
        float4 fv = f4p[i];
        float rn0 = r_[4 * i + 0] - cv.x;
        float rn1 = r_[4 * i + 1] - cv.y;
        float rn2 = r_[4 * i + 2] - cv.z;
        float rn3 = r_[4 * i + 3] - cv.w;
        float4 o;
        o.x = fv.x - rn0;
        o.y = fv.y - rn1;
        o.z = fv.z - rn2;
        o.w = fv.w - rn3;
        o4[i] = o;
      }
    }
    out_idx[(size_t)l * RVQ_N + g] = (float)ci;
  }
}

extern "C" void kernel_launch(void* const* d_in, const int* in_sizes, int n_in,
                              void* d_out, int out_size, void* d_ws,
                              size_t ws_size, hipStream_t stream) {
  const float* features = (const float*)d_in[0];   // [N, D]
  const float* codebooks = (const float*)d_in[1];  // [L, K, D]
  float* out_q = (float*)d_out;                    // [N, D]
  float* out_idx = (float*)d_out + (size_t)RVQ_N * RVQ_D;  // [L, N]

  const size_t comp_elems = (size_t)RVQ_L * RVQ_K * RVQ_D;  // 262144
  unsigned short* cb_hi = (unsigned short*)d_ws;
  unsigned short* cb_mid = cb_hi + comp_elems;
  float* cnorm = (float*)(cb_mid + comp_elems);   // [L*K] raw
  float* cnormB = cnorm + (size_t)RVQ_L * RVQ_K;  // [L*K] +256 biased

  hipLaunchKernelGGL(rvq_prep_split, dim3(comp_elems / 256), dim3(256), 0,
                     stream, codebooks, cb_hi, cb_mid);
  hipLaunchKernelGGL(rvq_cnorm_kernel, dim3((RVQ_L * RVQ_K) / 256), dim3(256),
                     0, stream, codebooks, cnorm, cnormB);
  hipLaunchKernelGGL(rvq_mfma_kernel, dim3(RVQ_N / 256), dim3(256), 0, stream,
                     features, codebooks, cb_hi, cb_mid, cnorm, cnormB, out_q,
                     out_idx);
}